// Round 14
// baseline (380.724 us; speedup 1.0000x reference)
//
#include <hip/hip_runtime.h>
#include <hip/hip_bf16.h>
#include <math.h>

typedef short bf16x8 __attribute__((ext_vector_type(8)));
typedef short bf16x4 __attribute__((ext_vector_type(4)));
typedef float f32x4 __attribute__((ext_vector_type(4)));

__device__ inline unsigned short f2bf(float f) {
  unsigned u = __float_as_uint(f);
  u += 0x7FFF + ((u >> 16) & 1);           // RNE
  return (unsigned short)(u >> 16);
}
__device__ inline float bf2f(unsigned short h) {
  return __uint_as_float(((unsigned)h) << 16);
}

// ---------------- CSR build ----------------

__global__ __launch_bounds__(256) void zero_i32(int* __restrict__ p, int n) {
  int i = blockIdx.x * 256 + threadIdx.x;
  if (i < n) p[i] = 0;
}

__global__ __launch_bounds__(256) void count_k(const int* __restrict__ dst, int* __restrict__ cnt, int e) {
  int i = blockIdx.x * 256 + threadIdx.x;
  if (i < e) atomicAdd(&cnt[dst[i]], 1);
}

__global__ __launch_bounds__(256) void scan_a(const int* __restrict__ cnt, int* __restrict__ bsum, int n) {
  int i = blockIdx.x * 256 + threadIdx.x;
  int v = (i < n) ? cnt[i] : 0;
#pragma unroll
  for (int o = 32; o > 0; o >>= 1) v += __shfl_xor(v, o);
  __shared__ int ws[4];
  if ((threadIdx.x & 63) == 0) ws[threadIdx.x >> 6] = v;
  __syncthreads();
  if (threadIdx.x == 0) bsum[blockIdx.x] = ws[0] + ws[1] + ws[2] + ws[3];
}

__global__ __launch_bounds__(256) void scan_b(const int* __restrict__ bsum, int* __restrict__ bpre,
                                              int* __restrict__ off_n, int nb) {
  __shared__ int s[256];
  int t = threadIdx.x;
  int v = (t < nb) ? bsum[t] : 0;
  s[t] = v;
  __syncthreads();
  for (int o = 1; o < 256; o <<= 1) {
    int u = (t >= o) ? s[t - o] : 0;
    __syncthreads();
    s[t] += u;
    __syncthreads();
  }
  if (t < nb) bpre[t] = s[t] - v;
  if (t == 255) off_n[0] = s[255];
}

// scan_c also computes dis = rsqrt(cnt+1)
__global__ __launch_bounds__(256) void scan_c(const int* __restrict__ cnt, const int* __restrict__ bpre,
                                              int* __restrict__ off, int* __restrict__ cursor,
                                              float* __restrict__ dis, int n) {
  __shared__ int s[256];
  int i = blockIdx.x * 256 + threadIdx.x;
  int t = threadIdx.x;
  int v = (i < n) ? cnt[i] : 0;
  s[t] = v;
  __syncthreads();
  for (int o = 1; o < 256; o <<= 1) {
    int u = (t >= o) ? s[t - o] : 0;
    __syncthreads();
    s[t] += u;
    __syncthreads();
  }
  if (i < n) {
    int ov = bpre[blockIdx.x] + s[t] - v;
    off[i] = ov;
    cursor[i] = ov;
    dis[i] = rsqrtf((float)v + 1.0f);
  }
}

__global__ __launch_bounds__(256) void scatter_k(const int* __restrict__ src, const int* __restrict__ dst,
                                                 int* __restrict__ cursor, int* __restrict__ csr, int e) {
  int i = blockIdx.x * 256 + threadIdx.x;
  if (i < e) {
    int p = atomicAdd(&cursor[dst[i]], 1);
    csr[p] = src[i];
  }
}

// ------- weight convert: W[K][N] fp32 -> Wc[N][K] bf16 -------

__global__ __launch_bounds__(256) void wconv_k(const float* __restrict__ W1, const float* __restrict__ Wr,
                                               const float* __restrict__ W2, const float* __restrict__ W3,
                                               const float* __restrict__ W4,
                                               short* __restrict__ o1, short* __restrict__ oR,
                                               short* __restrict__ o2, short* __restrict__ o3,
                                               short* __restrict__ o4) {
  int b = blockIdx.x;  // 960 rows total
  const float* W; short* O; int K, N, nr;
  if (b < 64)       { W = W1; O = o1; K = 128; N = 64;  nr = b; }
  else if (b < 128) { W = Wr; O = oR; K = 128; N = 64;  nr = b - 64; }
  else if (b < 384) { W = W2; O = o2; K = 64;  N = 256; nr = b - 128; }
  else if (b < 896) { W = W3; O = o3; K = 256; N = 512; nr = b - 384; }
  else              { W = W4; O = o4; K = 512; N = 64;  nr = b - 896; }
  for (int k = threadIdx.x; k < K; k += 256)
    O[(size_t)nr * K + k] = (short)f2bf(W[(size_t)k * N + nr]);
}

// ------- MFMA GEMM (generic): C[M,NTOT] = A[M,KT] @ Wc[NTOT,KT](bf16) -------

template<int KT, int NTOT, int WM, int WN, int BIAS, int RELU, int ABF, int OBF, int SPLIT, int SCL, int BLK>
__global__ __launch_bounds__(256, BLK) void mgemm(const void* __restrict__ Av,
                                                  const short* __restrict__ Wc,
                                                  const float* __restrict__ bias,
                                                  void* __restrict__ Cv, void* __restrict__ Cv2,
                                                  const float* __restrict__ scl, int M) {
  __shared__ short As[64 * WM][ABF ? 40 : 72];
  __shared__ short Bs[64 * WN][40];
  const int tid = threadIdx.x;
  const int row0 = blockIdx.x * (64 * WM);
  const int col0 = blockIdx.y * (64 * WN);
  const int w = tid >> 6, lane = tid & 63;
  const int wm = w / WN, wn = w % WN;
  const int rm = wm * 64, cn = wn * 64;
  const int lm = lane & 15, lk = (lane >> 4) * 8;

  f32x4 acc[4][4];
#pragma unroll
  for (int i = 0; i < 4; i++)
#pragma unroll
    for (int j = 0; j < 4; j++)
#pragma unroll
      for (int r = 0; r < 4; r++) acc[i][j][r] = 0.f;

  for (int k0 = 0; k0 < KT; k0 += 32) {
#pragma unroll
    for (int p = 0; p < WM; p++) {
      int r = (tid >> 2) + p * 64;
      int kseg = (tid & 3) * 8;
      int gr = row0 + r;
      if (ABF) {
        bf16x8 v = {0, 0, 0, 0, 0, 0, 0, 0};
        if (gr < M) v = *(const bf16x8*)((const short*)Av + (size_t)gr * KT + k0 + kseg);
        *(bf16x8*)&As[r][kseg] = v;
      } else {
        float4 v0 = {0.f, 0.f, 0.f, 0.f}, v1 = {0.f, 0.f, 0.f, 0.f};
        if (gr < M) {
          const float* ap = (const float*)Av + (size_t)gr * KT + k0 + kseg;
          v0 = *(const float4*)ap;
          v1 = *(const float4*)(ap + 4);
        }
        float vv[8] = {v0.x, v0.y, v0.z, v0.w, v1.x, v1.y, v1.z, v1.w};
        bf16x8 hv, lv;
#pragma unroll
        for (int j = 0; j < 8; j++) {
          unsigned short h = f2bf(vv[j]);
          hv[j] = (short)h;
          lv[j] = (short)f2bf(vv[j] - bf2f(h));
        }
        *(bf16x8*)&As[r][kseg] = hv;
        *(bf16x8*)&As[r][32 + kseg] = lv;
      }
    }
#pragma unroll
    for (int p = 0; p < WN; p++) {
      int nr = (tid >> 2) + p * 64;
      int seg = (tid & 3) * 8;
      *(bf16x8*)&Bs[nr][seg] = *(const bf16x8*)(Wc + (size_t)(col0 + nr) * KT + k0 + seg);
    }
    __syncthreads();

    bf16x8 ah[4], al[4], bb[4];
#pragma unroll
    for (int mt = 0; mt < 4; mt++) {
      ah[mt] = *(const bf16x8*)&As[rm + mt * 16 + lm][lk];
      if (!ABF) al[mt] = *(const bf16x8*)&As[rm + mt * 16 + lm][32 + lk];
    }
#pragma unroll
    for (int nt = 0; nt < 4; nt++) bb[nt] = *(const bf16x8*)&Bs[cn + nt * 16 + lm][lk];
#pragma unroll
    for (int mt = 0; mt < 4; mt++)
#pragma unroll
      for (int nt = 0; nt < 4; nt++) {
        acc[mt][nt] = __builtin_amdgcn_mfma_f32_16x16x32_bf16(ah[mt], bb[nt], acc[mt][nt], 0, 0, 0);
        if (!ABF)
          acc[mt][nt] = __builtin_amdgcn_mfma_f32_16x16x32_bf16(al[mt], bb[nt], acc[mt][nt], 0, 0, 0);
      }
    __syncthreads();
  }

  if (SPLIT) {
    short* epi = (short*)&As[0][0];   // 128*64 shorts = 16 KB
    if (wn == 0) {
#pragma unroll
      for (int mt = 0; mt < 4; mt++) {
        int lr = rm + mt * 16 + (lane >> 4) * 4;
#pragma unroll
        for (int r = 0; r < 4; r++) {
          int gr = row0 + lr + r;
          float sc = (SCL && gr < M) ? scl[gr] : 0.f;
#pragma unroll
          for (int nt = 0; nt < 4; nt++)
            epi[(lr + r) * 64 + nt * 16 + lm] = (short)f2bf(acc[mt][nt][r] * sc);
        }
      }
    } else {
#pragma unroll
      for (int mt = 0; mt < 4; mt++) {
        int grb = row0 + rm + mt * 16 + (lane >> 4) * 4;
#pragma unroll
        for (int nt = 0; nt < 4; nt++) {
          int gc = nt * 16 + lm;
          float bv = bias[gc];
#pragma unroll
          for (int r = 0; r < 4; r++) {
            int gr = grb + r;
            if (gr < M) ((float*)Cv2)[(size_t)gr * 64 + gc] = acc[mt][nt][r] + bv;
          }
        }
      }
    }
    __syncthreads();
    int base = tid * 32;
    int row = base >> 6, col = base & 63;
    int gr = row0 + row;
    if (gr < M) {
#pragma unroll
      for (int q = 0; q < 4; q++)
        *(bf16x8*)((short*)Cv + (size_t)gr * 64 + col + q * 8) = *(bf16x8*)&epi[base + q * 8];
    }
  } else if (OBF && WM == 1) {
    short* epi = &Bs[0][0];
    const int NCOL = 64 * WN;
    float bvv[4];
#pragma unroll
    for (int nt = 0; nt < 4; nt++) bvv[nt] = BIAS ? bias[col0 + cn + nt * 16 + lm] : 0.f;
#pragma unroll
    for (int mt = 0; mt < 4; mt++) {
      __syncthreads();
#pragma unroll
      for (int r = 0; r < 4; r++) {
        int gr = row0 + mt * 16 + (lane >> 4) * 4 + r;
        float sc = (SCL && gr < M) ? scl[gr] : 1.f;
#pragma unroll
        for (int nt = 0; nt < 4; nt++) {
          float v = acc[mt][nt][r] + bvv[nt];
          if (RELU) v = (v >= 0.f) ? v : 0.01f * v;
          if (SCL) v *= sc;
          epi[((lane >> 4) * 4 + r) * NCOL + cn + nt * 16 + lm] = (short)f2bf(v);
        }
      }
      __syncthreads();
      const int per = (16 * NCOL) / 256;
      int base = tid * per;
      int lr = base / NCOL, lc = base % NCOL;
      int gr = row0 + mt * 16 + lr;
      if (gr < M) {
#pragma unroll
        for (int q = 0; q < per / 8; q++)
          *(bf16x8*)((short*)Cv + (size_t)gr * NTOT + col0 + lc + q * 8) = *(bf16x8*)&epi[base + q * 8];
      }
    }
  } else {
#pragma unroll
    for (int mt = 0; mt < 4; mt++) {
      int grb = row0 + rm + mt * 16 + (lane >> 4) * 4;
#pragma unroll
      for (int nt = 0; nt < 4; nt++) {
        int gc = col0 + cn + nt * 16 + lm;
        float bv = BIAS ? bias[gc] : 0.f;
#pragma unroll
        for (int r = 0; r < 4; r++) {
          int gr = grb + r;
          if (gr < M) {
            float v = acc[mt][nt][r] + bv;
            if (RELU) v = (v >= 0.f) ? v : 0.01f * v;
            if (SCL) v *= scl[gr];
            if (OBF) ((short*)Cv)[(size_t)gr * NTOT + gc] = (short)f2bf(v);
            else     ((float*)Cv)[(size_t)gr * NTOT + gc] = v;
          }
        }
      }
    }
  }
}

// ------- fused layer3+layer4: t4 += dis * (leaky(z3 @ W3 + b3) @ W4), split-K -------
// R14: grid (nblk, 2); ky handles 8 of 16 h3 col-chunks. Single-buffer LDS
// (27 KB -> 5 blocks/CU), register prefetch keeps load latency off the
// critical path. Partials combined via fp32 atomicAdd (t4 pre-zeroed).

__global__ __launch_bounds__(256, 5) void fused34_k(const short* __restrict__ z3,
                                                    const short* __restrict__ W3c,  // [512][256] bf16
                                                    const float* __restrict__ b3,
                                                    const short* __restrict__ W4c,  // [64][512] bf16
                                                    const float* __restrict__ dis,
                                                    float* __restrict__ T4, int M) {
  __shared__ short Bs[32][264];  // W3 chunk: 32 n-rows x 256 k (16.9 KB)
  __shared__ short Hs[64][40];   // h3 chunk, A-layout (wave-private rows)
  __shared__ short Ws4[64][40];  // W4 chunk: 64 out x 32 k
  const int tid = threadIdx.x;
  const int row0 = blockIdx.x * 64;
  const int ky = blockIdx.y;            // 0 or 1: which half of the 16 chunks
  const int w = tid >> 6, lane = tid & 63;
  const int lm = lane & 15, lk = (lane >> 4) * 8;
  const int rquad = (lane >> 4) * 4;
  const int w4row = tid >> 2, w4seg = (tid & 3) * 8;

  // z3 A-fragments in registers (wave-private 16 rows, full K=256)
  bf16x8 afr[8];
  {
    int gr = row0 + w * 16 + lm;
    bool ok = gr < M;
    const short* zp = z3 + (size_t)gr * 256 + lk;
#pragma unroll
    for (int kc = 0; kc < 8; kc++) {
      bf16x8 v = {0, 0, 0, 0, 0, 0, 0, 0};
      if (ok) v = *(const bf16x8*)(zp + kc * 32);
      afr[kc] = v;
    }
  }

  f32x4 t4acc[4];
#pragma unroll
  for (int nt = 0; nt < 4; nt++)
#pragma unroll
    for (int r = 0; r < 4; r++) t4acc[nt][r] = 0.f;

  // prologue: prefetch chunk ky*8 into registers
  bf16x8 pw3[4];
  bf16x8 pw4;
  {
    int cg = ky * 8;
#pragma unroll
    for (int q = 0; q < 4; q++) {
      int flat = q * 2048 + tid * 8;
      pw3[q] = *(const bf16x8*)(W3c + (size_t)cg * 32 * 256 + flat);
    }
    pw4 = *(const bf16x8*)(W4c + (size_t)w4row * 512 + cg * 32 + w4seg);
  }

  for (int c = 0; c < 8; c++) {
    int cg = ky * 8 + c;
    // store prefetched chunk into LDS
#pragma unroll
    for (int q = 0; q < 4; q++) {
      int flat = q * 2048 + tid * 8;
      *(bf16x8*)&Bs[flat >> 8][flat & 255] = pw3[q];
    }
    *(bf16x8*)&Ws4[w4row][w4seg] = pw4;
    __syncthreads();
    // issue next chunk's loads (latency overlapped with MFMA below)
    if (c < 7) {
      int cn2 = cg + 1;
#pragma unroll
      for (int q = 0; q < 4; q++) {
        int flat = q * 2048 + tid * 8;
        pw3[q] = *(const bf16x8*)(W3c + (size_t)cn2 * 32 * 256 + flat);
      }
      pw4 = *(const bf16x8*)(W4c + (size_t)w4row * 512 + cn2 * 32 + w4seg);
    }

    // stage-1: h3 chunk (2 nt tiles), 16 MFMA
    f32x4 acc1[2];
#pragma unroll
    for (int nt = 0; nt < 2; nt++)
#pragma unroll
      for (int r = 0; r < 4; r++) acc1[nt][r] = 0.f;
#pragma unroll
    for (int k0 = 0; k0 < 8; k0++) {
      bf16x8 bb[2];
#pragma unroll
      for (int nt = 0; nt < 2; nt++) bb[nt] = *(const bf16x8*)&Bs[nt * 16 + lm][k0 * 32 + lk];
#pragma unroll
      for (int nt = 0; nt < 2; nt++)
        acc1[nt] = __builtin_amdgcn_mfma_f32_16x16x32_bf16(afr[k0], bb[nt], acc1[nt], 0, 0, 0);
    }
    // bias + leaky -> bf16 -> Hs (C->A layout, wave-private rows)
#pragma unroll
    for (int nt = 0; nt < 2; nt++) {
      float bv = b3[cg * 32 + nt * 16 + lm];
#pragma unroll
      for (int r = 0; r < 4; r++) {
        float v = acc1[nt][r] + bv;
        v = (v >= 0.f) ? v : 0.01f * v;
        Hs[w * 16 + rquad + r][nt * 16 + lm] = (short)f2bf(v);
      }
    }
    // stage-2: t4 += h3_chunk @ W4_chunk (k=32, 4 MFMA)
    {
      bf16x8 ah2 = *(const bf16x8*)&Hs[w * 16 + lm][lk];
      bf16x8 bb2[4];
#pragma unroll
      for (int nt = 0; nt < 4; nt++) bb2[nt] = *(const bf16x8*)&Ws4[nt * 16 + lm][lk];
#pragma unroll
      for (int nt = 0; nt < 4; nt++)
        t4acc[nt] = __builtin_amdgcn_mfma_f32_16x16x32_bf16(ah2, bb2[nt], t4acc[nt], 0, 0, 0);
    }
    __syncthreads();
  }
  // epilogue: atomic-accumulate dis-scaled partial into t4
#pragma unroll
  for (int r = 0; r < 4; r++) {
    int gr = row0 + w * 16 + rquad + r;
    if (gr < M) {
      float sc = dis[gr];
#pragma unroll
      for (int nt = 0; nt < 4; nt++) {
        int gc = nt * 16 + lm;
        atomicAdd(&T4[(size_t)gr * 64 + gc], t4acc[nt][r] * sc);
      }
    }
  }
}

// ---------------- Aggregation (dis-free; rows pre-scaled by dis) ----------------

template<int BR, int OSCL>
__global__ __launch_bounds__(256) void aggb64_k(const short* __restrict__ T, const float* __restrict__ dis,
                                                const int* __restrict__ off, const int* __restrict__ csr,
                                                const float* __restrict__ bias, short* __restrict__ Out, int n) {
  int wid = (blockIdx.x * 256 + threadIdx.x) >> 6;
  int lane = threadIdx.x & 63;
  if (wid >= n) return;
  float di = dis[wid];
  int e0 = off[wid], e1 = off[wid + 1];
  float acc = bf2f((unsigned short)T[(size_t)wid * 64 + lane]);
  int e = e0;
  for (; e + 8 <= e1; e += 8) {
    int j0 = csr[e], j1 = csr[e + 1], j2 = csr[e + 2], j3 = csr[e + 3];
    int j4 = csr[e + 4], j5 = csr[e + 5], j6 = csr[e + 6], j7 = csr[e + 7];
    float v0 = bf2f((unsigned short)T[(size_t)j0 * 64 + lane]);
    float v1 = bf2f((unsigned short)T[(size_t)j1 * 64 + lane]);
    float v2 = bf2f((unsigned short)T[(size_t)j2 * 64 + lane]);
    float v3 = bf2f((unsigned short)T[(size_t)j3 * 64 + lane]);
    float v4 = bf2f((unsigned short)T[(size_t)j4 * 64 + lane]);
    float v5 = bf2f((unsigned short)T[(size_t)j5 * 64 + lane]);
    float v6 = bf2f((unsigned short)T[(size_t)j6 * 64 + lane]);
    float v7 = bf2f((unsigned short)T[(size_t)j7 * 64 + lane]);
    acc += ((v0 + v1) + (v2 + v3)) + ((v4 + v5) + (v6 + v7));
  }
  for (; e + 4 <= e1; e += 4) {
    int j0 = csr[e], j1 = csr[e + 1], j2 = csr[e + 2], j3 = csr[e + 3];
    float v0 = bf2f((unsigned short)T[(size_t)j0 * 64 + lane]);
    float v1 = bf2f((unsigned short)T[(size_t)j1 * 64 + lane]);
    float v2 = bf2f((unsigned short)T[(size_t)j2 * 64 + lane]);
    float v3 = bf2f((unsigned short)T[(size_t)j3 * 64 + lane]);
    acc += (v0 + v1) + (v2 + v3);
  }
  for (; e < e1; e++) acc += bf2f((unsigned short)T[(size_t)csr[e] * 64 + lane]);
  float v = di * acc;
  if (BR) {
    v += bias[lane];
    v = (v >= 0.f) ? v : 0.01f * v;
  }
  if (OSCL) v *= di;
  Out[(size_t)wid * 64 + lane] = (short)f2bf(v);
}

// layer-4 tail fused: hn = LN( leaky(di*sum(t4) + b4) + resid )
__global__ __launch_bounds__(256) void agg64_ln_k(const float* __restrict__ T, const float* __restrict__ dis,
                                                  const int* __restrict__ off, const int* __restrict__ csr,
                                                  const float* __restrict__ bias, const float* __restrict__ resid,
                                                  const float* __restrict__ g, const float* __restrict__ b,
                                                  float* __restrict__ outh, int n) {
  int wid = (blockIdx.x * 256 + threadIdx.x) >> 6;
  int lane = threadIdx.x & 63;
  if (wid >= n) return;
  float di = dis[wid];
  int e0 = off[wid], e1 = off[wid + 1];
  float acc = T[(size_t)wid * 64 + lane];
  int e = e0;
  for (; e + 8 <= e1; e += 8) {
    int j0 = csr[e], j1 = csr[e + 1], j2 = csr[e + 2], j3 = csr[e + 3];
    int j4 = csr[e + 4], j5 = csr[e + 5], j6 = csr[e + 6], j7 = csr[e + 7];
    float v0 = T[(size_t)j0 * 64 + lane];
    float v1 = T[(size_t)j1 * 64 + lane];
    float v2 = T[(size_t)j2 * 64 + lane];
    float v3 = T[(size_t)j3 * 64 + lane];
    float v4 = T[(size_t)j4 * 64 + lane];
    float v5 = T[(size_t)j5 * 64 + lane];
    float v6 = T[(size_t)j6 * 64 + lane];
    float v7 = T[(size_t)j7 * 64 + lane];
    acc += ((v0 + v1) + (v2 + v3)) + ((v4 + v5) + (v6 + v7));
  }
  for (; e + 4 <= e1; e += 4) {
    int j0 = csr[e], j1 = csr[e + 1], j2 = csr[e + 2], j3 = csr[e + 3];
    float v0 = T[(size_t)j0 * 64 + lane];
    float v1 = T[(size_t)j1 * 64 + lane];
    float v2 = T[(size_t)j2 * 64 + lane];
    float v3 = T[(size_t)j3 * 64 + lane];
    acc += (v0 + v1) + (v2 + v3);
  }
  for (; e < e1; e++) acc += T[(size_t)csr[e] * 64 + lane];
  float v = di * acc + bias[lane];
  v = (v >= 0.f) ? v : 0.01f * v;
  v += resid[(size_t)wid * 64 + lane];
  float s = v, ss = v * v;
#pragma unroll
  for (int o = 32; o > 0; o >>= 1) {
    s += __shfl_xor(s, o);
    ss += __shfl_xor(ss, o);
  }
  float m = s * (1.f / 64.f);
  float var = ss * (1.f / 64.f) - m * m;
  float y = (v - m) * rsqrtf(var + 1e-5f) * g[lane] + b[lane];
  outh[(size_t)wid * 64 + lane] = y;
}

// bf16 gather for the 256-dim layer: z3 = di*(sum + self)
__global__ __launch_bounds__(256) void agg256b_k(const short* __restrict__ T, const float* __restrict__ dis,
                                                 const int* __restrict__ off, const int* __restrict__ csr,
                                                 short* __restrict__ Out, int n) {
  int wid = (blockIdx.x * 256 + threadIdx.x) >> 6;
  int lane = threadIdx.x & 63;
  if (wid >= n) return;
  float di = dis[wid];
  int e0 = off[wid], e1 = off[wid + 1];
  bf16x4 sf = *(const bf16x4*)&T[(size_t)wid * 256 + lane * 4];
  float a0 = bf2f((unsigned short)sf[0]);
  float a1 = bf2f((unsigned short)sf[1]);
  float a2 = bf2f((unsigned short)sf[2]);
  float a3 = bf2f((unsigned short)sf[3]);
  int e = e0;
  for (; e + 8 <= e1; e += 8) {
    bf16x4 t[8];
#pragma unroll
    for (int q = 0; q < 8; q++) t[q] = *(const bf16x4*)&T[(size_t)csr[e + q] * 256 + lane * 4];
#pragma unroll
    for (int q = 0; q < 8; q++) {
      a0 += bf2f((unsigned short)t[q][0]);
      a1 += bf2f((unsigned short)t[q][1]);
      a2 += bf2f((unsigned short)t[q][2]);
      a3 += bf2f((unsigned short)t[q][3]);
    }
  }
  for (; e + 4 <= e1; e += 4) {
    bf16x4 t[4];
#pragma unroll
    for (int q = 0; q < 4; q++) t[q] = *(const bf16x4*)&T[(size_t)csr[e + q] * 256 + lane * 4];
#pragma unroll
    for (int q = 0; q < 4; q++) {
      a0 += bf2f((unsigned short)t[q][0]);
      a1 += bf2f((unsigned short)t[q][1]);
      a2 += bf2f((unsigned short)t[q][2]);
      a3 += bf2f((unsigned short)t[q][3]);
    }
  }
  for (; e < e1; e++) {
    bf16x4 t = *(const bf16x4*)&T[(size_t)csr[e] * 256 + lane * 4];
    a0 += bf2f((unsigned short)t[0]);
    a1 += bf2f((unsigned short)t[1]);
    a2 += bf2f((unsigned short)t[2]);
    a3 += bf2f((unsigned short)t[3]);
  }
  bf16x4 o;
  o[0] = (short)f2bf(di * a0);
  o[1] = (short)f2bf(di * a1);
  o[2] = (short)f2bf(di * a2);
  o[3] = (short)f2bf(di * a3);
  *(bf16x4*)&Out[(size_t)wid * 256 + lane * 4] = o;
}

// ---------------- per-graph max pool + final MLP (fused, one block per graph) ----------------

__global__ __launch_bounds__(256) void pool_mlp_k(const float* __restrict__ hn,
                                                  const float* __restrict__ fc1W, const float* __restrict__ fc1b,
                                                  const float* __restrict__ fng, const float* __restrict__ fnb,
                                                  const float* __restrict__ fc2W, const float* __restrict__ fc2b,
                                                  float* __restrict__ out, int n) {
  const int G = 64;
  int g = blockIdx.x;
  int f = threadIdx.x & 63, c = threadIdx.x >> 6;
  long long s0 = ((long long)g * n + G - 1) / G;
  long long e0 = ((long long)(g + 1) * n + G - 1) / G;
  float m = -INFINITY;
  for (long long i = s0 + c; i < e0; i += 4) m = fmaxf(m, hn[(size_t)i * 64 + f]);
  __shared__ float red[4][64];
  __shared__ float ps[64], qs[64];
  red[c][f] = m;
  __syncthreads();
  if (c == 0) ps[f] = fmaxf(fmaxf(red[0][f], red[1][f]), fmaxf(red[2][f], red[3][f]));
  __syncthreads();
  if (threadIdx.x < 64) {
    int lane = threadIdx.x;
    float q = fc1b[lane];
#pragma unroll 8
    for (int k = 0; k < 64; k++) q = fmaf(ps[k], fc1W[k * 64 + lane], q);
    float s = q, ss = q * q;
#pragma unroll
    for (int o = 32; o > 0; o >>= 1) {
      s += __shfl_xor(s, o);
      ss += __shfl_xor(ss, o);
    }
    float mm = s * (1.f / 64.f);
    float var = ss * (1.f / 64.f) - mm * mm;
    float y = (q - mm) * rsqrtf(var + 1e-5f) * fng[lane] + fnb[lane];
    y = (y >= 0.f) ? y : 0.01f * y;
    qs[lane] = y;
    __builtin_amdgcn_wave_barrier();
    if (lane < 16) {
      float o = fc2b[lane];
#pragma unroll 8
      for (int k = 0; k < 64; k++) o = fmaf(qs[k], fc2W[k * 16 + lane], o);
      out[g * 16 + lane] = o;
    }
  }
}

// ---------------- launch ----------------

extern "C" void kernel_launch(void* const* d_in, const int* in_sizes, int n_in,
                              void* d_out, int out_size, void* d_ws, size_t ws_size,
                              hipStream_t stream) {
  const float* x   = (const float*)d_in[0];
  const int*   ei  = (const int*)d_in[1];
  const float* W1  = (const float*)d_in[3];
  const float* b1  = (const float*)d_in[4];
  const float* W2  = (const float*)d_in[5];
  const float* b2  = (const float*)d_in[6];
  const float* W3  = (const float*)d_in[7];
  const float* b3  = (const float*)d_in[8];
  const float* W4  = (const float*)d_in[9];
  const float* b4  = (const float*)d_in[10];
  const float* Wr  = (const float*)d_in[11];
  const float* br  = (const float*)d_in[12];
  const float* lng = (const float*)d_in[13];
  const float* lnb = (const float*)d_in[14];
  const float* f1W = (const float*)d_in[15];
  const float* f1b = (const float*)d_in[16];
  const float* fng = (const float*)d_in[17];
  const float* fnb = (const float*)d_in[18];
  const float* f2W = (const float*)d_in[19];
  const float* f2b = (const float*)d_in[20];

  int n = in_sizes[0] / 128;   // 50000
  int e = in_sizes[1] / 2;     // 400000
  const int* src = ei;
  const int* dst = ei + e;

  float* arena = (float*)d_ws;
  float* resid = arena;
  short* h2b   = (short*)(arena + (size_t)64 * n);
  float* t4    = arena + (size_t)64 * n;
  short* z3b   = (short*)(arena + (size_t)192 * n);
  float* hn    = arena + (size_t)192 * n;
  short* t1b   = (short*)(arena + (size_t)320 * n);
  short* h1b   = (short*)(arena + (size_t)352 * n);
  short* z2b   = (short*)(arena + (size_t)384 * n);
  float* dis   = arena + (size_t)448 * n;  // n
  int* cnt    = (int*)(dis + n);           // n
  int* off    = cnt + n;                   // n+1
  int* cursor = off + n + 1;               // n
  int* csr    = cursor + n;                // e
  int* bsum   = csr + e;                   // 256
  int* bpre   = bsum + 256;                // 256
  float* pool = (float*)(bpre + 256);      // 64*64 (unused, layout keep)
  size_t wq = (((size_t)(pool + 4096)) + 15) & ~(size_t)15;
  short* wc1 = (short*)wq;                 // 64 x 128   (wc1||wcR = fused 128 x 128)
  short* wcR = wc1 + 8192;                 // 64 x 128
  short* wc2 = wcR + 8192;                 // 256 x 64
  short* wc3 = wc2 + 16384;                // 512 x 256
  short* wc4 = wc3 + 131072;               // 64 x 512
  size_t need = ((char*)(wc4 + 32768) - (char*)d_ws) + 64;
  if (ws_size < need) return;

  int nb_n = (n + 255) / 256;     // 196
  int nb_e = (e + 255) / 256;
  int nb_w = (n + 3) / 4;         // one wave per node
  int g_wide = (n + 63) / 64;     // 782
  int g_fused = (n + 127) / 128;  // 391

  // weights -> bf16 [N][K]
  wconv_k<<<960, 256, 0, stream>>>(W1, Wr, W2, W3, W4, wc1, wcR, wc2, wc3, wc4);

  // degree + CSR (hierarchical scan; dis fused into scan_c)
  zero_i32<<<nb_n, 256, 0, stream>>>(cnt, n);
  count_k<<<nb_e, 256, 0, stream>>>(dst, cnt, e);
  scan_a<<<nb_n, 256, 0, stream>>>(cnt, bsum, n);
  scan_b<<<1, 256, 0, stream>>>(bsum, bpre, off + n, nb_n);
  scan_c<<<nb_n, 256, 0, stream>>>(cnt, bpre, off, cursor, dis, n);
  scatter_k<<<nb_e, 256, 0, stream>>>(src, dst, cursor, csr, e);

  // fused L1 + residual: t1b = bf16(dis*(x@W1)); resid = x@Wr + br
  mgemm<128, 128, 2, 2, 1, 0, 0, 0, 1, 1, 4><<<dim3(g_fused, 1), 256, 0, stream>>>(x, wc1, br, t1b, resid, dis, n);
  // h1b = bf16( dis * leaky(di*sum(t1) + b1) )
  aggb64_k<1, 1><<<nb_w, 256, 0, stream>>>(t1b, dis, off, csr, b1, h1b, n);
  // z2b = bf16( di * sum(h1) )
  aggb64_k<0, 0><<<nb_w, 256, 0, stream>>>(h1b, dis, off, csr, nullptr, z2b, n);
  // h2b = bf16( dis * leaky(z2@W2 + b2) )
  mgemm<64, 256, 1, 4, 1, 1, 1, 1, 0, 1, 5><<<dim3(g_wide, 1), 256, 0, stream>>>(z2b, wc2, b2, h2b, nullptr, dis, n);
  // z3b = bf16( di * sum(h2b) )
  agg256b_k<<<nb_w, 256, 0, stream>>>(h2b, dis, off, csr, z3b, n);
  // t4 = dis * (leaky(z3@W3+b3) @ W4)   — split-K over 2 blocks, atomic combine
  hipMemsetAsync(t4, 0, (size_t)n * 64 * sizeof(float), stream);
  fused34_k<<<dim3(g_wide, 2), 256, 0, stream>>>(z3b, wc3, b3, wc4, dis, t4, n);
  // hn = LN( leaky(di*sum(t4) + b4) + resid )
  agg64_ln_k<<<nb_w, 256, 0, stream>>>(t4, dis, off, csr, b4, resid, lng, lnb, hn, n);
  // pool + MLP fused
  pool_mlp_k<<<64, 256, 0, stream>>>(hn, f1W, f1b, fng, fnb, f2W, f2b, (float*)d_out, n);
}

// Round 15
// 375.774 us; speedup vs baseline: 1.0132x; 1.0132x over previous
//
#include <hip/hip_runtime.h>
#include <hip/hip_bf16.h>
#include <math.h>

typedef short bf16x8 __attribute__((ext_vector_type(8)));
typedef short bf16x4 __attribute__((ext_vector_type(4)));
typedef float f32x4 __attribute__((ext_vector_type(4)));

__device__ inline unsigned short f2bf(float f) {
  unsigned u = __float_as_uint(f);
  u += 0x7FFF + ((u >> 16) & 1);           // RNE
  return (unsigned short)(u >> 16);
}
__device__ inline float bf2f(unsigned short h) {
  return __uint_as_float(((unsigned)h) << 16);
}

// ---------------- CSR build ----------------

__global__ __launch_bounds__(256) void count_k(const int* __restrict__ dst, int* __restrict__ cnt, int e) {
  int i = blockIdx.x * 256 + threadIdx.x;
  if (i < e) atomicAdd(&cnt[dst[i]], 1);
}

__global__ __launch_bounds__(256) void scan_a(const int* __restrict__ cnt, int* __restrict__ bsum, int n) {
  int i = blockIdx.x * 256 + threadIdx.x;
  int v = (i < n) ? cnt[i] : 0;
#pragma unroll
  for (int o = 32; o > 0; o >>= 1) v += __shfl_xor(v, o);
  __shared__ int ws[4];
  if ((threadIdx.x & 63) == 0) ws[threadIdx.x >> 6] = v;
  __syncthreads();
  if (threadIdx.x == 0) bsum[blockIdx.x] = ws[0] + ws[1] + ws[2] + ws[3];
}

__global__ __launch_bounds__(256) void scan_b(const int* __restrict__ bsum, int* __restrict__ bpre,
                                              int* __restrict__ off_n, int nb) {
  __shared__ int s[256];
  int t = threadIdx.x;
  int v = (t < nb) ? bsum[t] : 0;
  s[t] = v;
  __syncthreads();
  for (int o = 1; o < 256; o <<= 1) {
    int u = (t >= o) ? s[t - o] : 0;
    __syncthreads();
    s[t] += u;
    __syncthreads();
  }
  if (t < nb) bpre[t] = s[t] - v;
  if (t == 255) off_n[0] = s[255];
}

// scan_c also computes dis = rsqrt(cnt+1)
__global__ __launch_bounds__(256) void scan_c(const int* __restrict__ cnt, const int* __restrict__ bpre,
                                              int* __restrict__ off, int* __restrict__ cursor,
                                              float* __restrict__ dis, int n) {
  __shared__ int s[256];
  int i = blockIdx.x * 256 + threadIdx.x;
  int t = threadIdx.x;
  int v = (i < n) ? cnt[i] : 0;
  s[t] = v;
  __syncthreads();
  for (int o = 1; o < 256; o <<= 1) {
    int u = (t >= o) ? s[t - o] : 0;
    __syncthreads();
    s[t] += u;
    __syncthreads();
  }
  if (i < n) {
    int ov = bpre[blockIdx.x] + s[t] - v;
    off[i] = ov;
    cursor[i] = ov;
    dis[i] = rsqrtf((float)v + 1.0f);
  }
}

__global__ __launch_bounds__(256) void scatter_k(const int* __restrict__ src, const int* __restrict__ dst,
                                                 int* __restrict__ cursor, int* __restrict__ csr, int e) {
  int i = blockIdx.x * 256 + threadIdx.x;
  if (i < e) {
    int p = atomicAdd(&cursor[dst[i]], 1);
    csr[p] = src[i];
  }
}

// ------- weight convert: W[K][N] fp32 -> Wc[N][K] bf16 -------

__global__ __launch_bounds__(256) void wconv_k(const float* __restrict__ W1, const float* __restrict__ Wr,
                                               const float* __restrict__ W2, const float* __restrict__ W3,
                                               const float* __restrict__ W4,
                                               short* __restrict__ o1, short* __restrict__ oR,
                                               short* __restrict__ o2, short* __restrict__ o3,
                                               short* __restrict__ o4) {
  int b = blockIdx.x;  // 960 rows total
  const float* W; short* O; int K, N, nr;
  if (b < 64)       { W = W1; O = o1; K = 128; N = 64;  nr = b; }
  else if (b < 128) { W = Wr; O = oR; K = 128; N = 64;  nr = b - 64; }
  else if (b < 384) { W = W2; O = o2; K = 64;  N = 256; nr = b - 128; }
  else if (b < 896) { W = W3; O = o3; K = 256; N = 512; nr = b - 384; }
  else              { W = W4; O = o4; K = 512; N = 64;  nr = b - 896; }
  for (int k = threadIdx.x; k < K; k += 256)
    O[(size_t)nr * K + k] = (short)f2bf(W[(size_t)k * N + nr]);
}

// ------- MFMA GEMM (generic): C[M,NTOT] = A[M,KT] @ Wc[NTOT,KT](bf16) -------

template<int KT, int NTOT, int WM, int WN, int BIAS, int RELU, int ABF, int OBF, int SPLIT, int SCL, int BLK>
__global__ __launch_bounds__(256, BLK) void mgemm(const void* __restrict__ Av,
                                                  const short* __restrict__ Wc,
                                                  const float* __restrict__ bias,
                                                  void* __restrict__ Cv, void* __restrict__ Cv2,
                                                  const float* __restrict__ scl, int M) {
  __shared__ short As[64 * WM][ABF ? 40 : 72];
  __shared__ short Bs[64 * WN][40];
  const int tid = threadIdx.x;
  const int row0 = blockIdx.x * (64 * WM);
  const int col0 = blockIdx.y * (64 * WN);
  const int w = tid >> 6, lane = tid & 63;
  const int wm = w / WN, wn = w % WN;
  const int rm = wm * 64, cn = wn * 64;
  const int lm = lane & 15, lk = (lane >> 4) * 8;

  f32x4 acc[4][4];
#pragma unroll
  for (int i = 0; i < 4; i++)
#pragma unroll
    for (int j = 0; j < 4; j++)
#pragma unroll
      for (int r = 0; r < 4; r++) acc[i][j][r] = 0.f;

  for (int k0 = 0; k0 < KT; k0 += 32) {
#pragma unroll
    for (int p = 0; p < WM; p++) {
      int r = (tid >> 2) + p * 64;
      int kseg = (tid & 3) * 8;
      int gr = row0 + r;
      if (ABF) {
        bf16x8 v = {0, 0, 0, 0, 0, 0, 0, 0};
        if (gr < M) v = *(const bf16x8*)((const short*)Av + (size_t)gr * KT + k0 + kseg);
        *(bf16x8*)&As[r][kseg] = v;
      } else {
        float4 v0 = {0.f, 0.f, 0.f, 0.f}, v1 = {0.f, 0.f, 0.f, 0.f};
        if (gr < M) {
          const float* ap = (const float*)Av + (size_t)gr * KT + k0 + kseg;
          v0 = *(const float4*)ap;
          v1 = *(const float4*)(ap + 4);
        }
        float vv[8] = {v0.x, v0.y, v0.z, v0.w, v1.x, v1.y, v1.z, v1.w};
        bf16x8 hv, lv;
#pragma unroll
        for (int j = 0; j < 8; j++) {
          unsigned short h = f2bf(vv[j]);
          hv[j] = (short)h;
          lv[j] = (short)f2bf(vv[j] - bf2f(h));
        }
        *(bf16x8*)&As[r][kseg] = hv;
        *(bf16x8*)&As[r][32 + kseg] = lv;
      }
    }
#pragma unroll
    for (int p = 0; p < WN; p++) {
      int nr = (tid >> 2) + p * 64;
      int seg = (tid & 3) * 8;
      *(bf16x8*)&Bs[nr][seg] = *(const bf16x8*)(Wc + (size_t)(col0 + nr) * KT + k0 + seg);
    }
    __syncthreads();

    bf16x8 ah[4], al[4], bb[4];
#pragma unroll
    for (int mt = 0; mt < 4; mt++) {
      ah[mt] = *(const bf16x8*)&As[rm + mt * 16 + lm][lk];
      if (!ABF) al[mt] = *(const bf16x8*)&As[rm + mt * 16 + lm][32 + lk];
    }
#pragma unroll
    for (int nt = 0; nt < 4; nt++) bb[nt] = *(const bf16x8*)&Bs[cn + nt * 16 + lm][lk];
#pragma unroll
    for (int mt = 0; mt < 4; mt++)
#pragma unroll
      for (int nt = 0; nt < 4; nt++) {
        acc[mt][nt] = __builtin_amdgcn_mfma_f32_16x16x32_bf16(ah[mt], bb[nt], acc[mt][nt], 0, 0, 0);
        if (!ABF)
          acc[mt][nt] = __builtin_amdgcn_mfma_f32_16x16x32_bf16(al[mt], bb[nt], acc[mt][nt], 0, 0, 0);
      }
    __syncthreads();
  }

  if (SPLIT) {
    short* epi = (short*)&As[0][0];   // 128*64 shorts = 16 KB
    if (wn == 0) {
#pragma unroll
      for (int mt = 0; mt < 4; mt++) {
        int lr = rm + mt * 16 + (lane >> 4) * 4;
#pragma unroll
        for (int r = 0; r < 4; r++) {
          int gr = row0 + lr + r;
          float sc = (SCL && gr < M) ? scl[gr] : 0.f;
#pragma unroll
          for (int nt = 0; nt < 4; nt++)
            epi[(lr + r) * 64 + nt * 16 + lm] = (short)f2bf(acc[mt][nt][r] * sc);
        }
      }
    } else {
#pragma unroll
      for (int mt = 0; mt < 4; mt++) {
        int grb = row0 + rm + mt * 16 + (lane >> 4) * 4;
#pragma unroll
        for (int nt = 0; nt < 4; nt++) {
          int gc = nt * 16 + lm;
          float bv = bias[gc];
#pragma unroll
          for (int r = 0; r < 4; r++) {
            int gr = grb + r;
            if (gr < M) ((float*)Cv2)[(size_t)gr * 64 + gc] = acc[mt][nt][r] + bv;
          }
        }
      }
    }
    __syncthreads();
    int base = tid * 32;
    int row = base >> 6, col = base & 63;
    int gr = row0 + row;
    if (gr < M) {
#pragma unroll
      for (int q = 0; q < 4; q++)
        *(bf16x8*)((short*)Cv + (size_t)gr * 64 + col + q * 8) = *(bf16x8*)&epi[base + q * 8];
    }
  } else if (OBF && WM == 1) {
    short* epi = &Bs[0][0];
    const int NCOL = 64 * WN;
    float bvv[4];
#pragma unroll
    for (int nt = 0; nt < 4; nt++) bvv[nt] = BIAS ? bias[col0 + cn + nt * 16 + lm] : 0.f;
#pragma unroll
    for (int mt = 0; mt < 4; mt++) {
      __syncthreads();
#pragma unroll
      for (int r = 0; r < 4; r++) {
        int gr = row0 + mt * 16 + (lane >> 4) * 4 + r;
        float sc = (SCL && gr < M) ? scl[gr] : 1.f;
#pragma unroll
        for (int nt = 0; nt < 4; nt++) {
          float v = acc[mt][nt][r] + bvv[nt];
          if (RELU) v = (v >= 0.f) ? v : 0.01f * v;
          if (SCL) v *= sc;
          epi[((lane >> 4) * 4 + r) * NCOL + cn + nt * 16 + lm] = (short)f2bf(v);
        }
      }
      __syncthreads();
      const int per = (16 * NCOL) / 256;
      int base = tid * per;
      int lr = base / NCOL, lc = base % NCOL;
      int gr = row0 + mt * 16 + lr;
      if (gr < M) {
#pragma unroll
        for (int q = 0; q < per / 8; q++)
          *(bf16x8*)((short*)Cv + (size_t)gr * NTOT + col0 + lc + q * 8) = *(bf16x8*)&epi[base + q * 8];
      }
    }
  } else {
#pragma unroll
    for (int mt = 0; mt < 4; mt++) {
      int grb = row0 + rm + mt * 16 + (lane >> 4) * 4;
#pragma unroll
      for (int nt = 0; nt < 4; nt++) {
        int gc = col0 + cn + nt * 16 + lm;
        float bv = BIAS ? bias[gc] : 0.f;
#pragma unroll
        for (int r = 0; r < 4; r++) {
          int gr = grb + r;
          if (gr < M) {
            float v = acc[mt][nt][r] + bv;
            if (RELU) v = (v >= 0.f) ? v : 0.01f * v;
            if (SCL) v *= scl[gr];
            if (OBF) ((short*)Cv)[(size_t)gr * NTOT + gc] = (short)f2bf(v);
            else     ((float*)Cv)[(size_t)gr * NTOT + gc] = v;
          }
        }
      }
    }
  }
}

// ------- fused layer3+layer4: t4b = bf16( dis * (leaky(z3 @ W3 + b3) @ W4) ) -------
// R15: R13 ping-pong structure (best measured, 43.6 us) + bf16 staged epilogue.

__global__ __launch_bounds__(256, 3) void fused34_k(const short* __restrict__ z3,
                                                    const short* __restrict__ W3c,  // [512][256] bf16
                                                    const float* __restrict__ b3,
                                                    const short* __restrict__ W4c,  // [64][512] bf16
                                                    const float* __restrict__ dis,
                                                    short* __restrict__ T4, int M) {
  __shared__ short Bs[2][32][264];  // W3 chunk ping-pong (2 x 16.9 KB)
  __shared__ short Ws4[2][64][40];  // W4 chunk ping-pong (2 x 5 KB)
  __shared__ short Hs[64][40];      // h3 chunk, A-layout (wave-private rows)
  const int tid = threadIdx.x;
  const int row0 = blockIdx.x * 64;
  const int w = tid >> 6, lane = tid & 63;
  const int lm = lane & 15, lk = (lane >> 4) * 8;
  const int rquad = (lane >> 4) * 4;
  const int w4row = tid >> 2, w4seg = (tid & 3) * 8;

  // z3 A-fragments in registers (wave-private 16 rows, full K=256)
  bf16x8 afr[8];
  {
    int gr = row0 + w * 16 + lm;
    bool ok = gr < M;
    const short* zp = z3 + (size_t)gr * 256 + lk;
#pragma unroll
    for (int kc = 0; kc < 8; kc++) {
      bf16x8 v = {0, 0, 0, 0, 0, 0, 0, 0};
      if (ok) v = *(const bf16x8*)(zp + kc * 32);
      afr[kc] = v;
    }
  }

  f32x4 t4acc[4];
#pragma unroll
  for (int nt = 0; nt < 4; nt++)
#pragma unroll
    for (int r = 0; r < 4; r++) t4acc[nt][r] = 0.f;

  // prologue: load + store chunk 0
  bf16x8 pw3[4];
  bf16x8 pw4;
#pragma unroll
  for (int q = 0; q < 4; q++) {
    int flat = q * 2048 + tid * 8;
    pw3[q] = *(const bf16x8*)(W3c + flat);
  }
  pw4 = *(const bf16x8*)(W4c + (size_t)w4row * 512 + w4seg);
#pragma unroll
  for (int q = 0; q < 4; q++) {
    int flat = q * 2048 + tid * 8;
    *(bf16x8*)&Bs[0][flat >> 8][flat & 255] = pw3[q];
  }
  *(bf16x8*)&Ws4[0][w4row][w4seg] = pw4;
  __syncthreads();

  for (int c = 0; c < 16; c++) {
    int cur = c & 1, nxt = cur ^ 1;
    // issue next chunk's global loads (latency overlapped with MFMA below)
    if (c < 15) {
#pragma unroll
      for (int q = 0; q < 4; q++) {
        int flat = q * 2048 + tid * 8;
        pw3[q] = *(const bf16x8*)(W3c + (size_t)(c + 1) * 32 * 256 + flat);
      }
      pw4 = *(const bf16x8*)(W4c + (size_t)w4row * 512 + (c + 1) * 32 + w4seg);
    }

    // stage-1: h3 chunk (2 nt tiles), 16 MFMA
    f32x4 acc1[2];
#pragma unroll
    for (int nt = 0; nt < 2; nt++)
#pragma unroll
      for (int r = 0; r < 4; r++) acc1[nt][r] = 0.f;
#pragma unroll
    for (int k0 = 0; k0 < 8; k0++) {
      bf16x8 bb[2];
#pragma unroll
      for (int nt = 0; nt < 2; nt++) bb[nt] = *(const bf16x8*)&Bs[cur][nt * 16 + lm][k0 * 32 + lk];
#pragma unroll
      for (int nt = 0; nt < 2; nt++)
        acc1[nt] = __builtin_amdgcn_mfma_f32_16x16x32_bf16(afr[k0], bb[nt], acc1[nt], 0, 0, 0);
    }
    // bias + leaky -> bf16 -> Hs (C->A layout, wave-private rows)
#pragma unroll
    for (int nt = 0; nt < 2; nt++) {
      float bv = b3[c * 32 + nt * 16 + lm];
#pragma unroll
      for (int r = 0; r < 4; r++) {
        float v = acc1[nt][r] + bv;
        v = (v >= 0.f) ? v : 0.01f * v;
        Hs[w * 16 + rquad + r][nt * 16 + lm] = (short)f2bf(v);
      }
    }
    // stage-2: t4 += h3_chunk @ W4_chunk (k=32, 4 MFMA)
    {
      bf16x8 ah2 = *(const bf16x8*)&Hs[w * 16 + lm][lk];
      bf16x8 bb2[4];
#pragma unroll
      for (int nt = 0; nt < 4; nt++) bb2[nt] = *(const bf16x8*)&Ws4[cur][nt * 16 + lm][lk];
#pragma unroll
      for (int nt = 0; nt < 4; nt++)
        t4acc[nt] = __builtin_amdgcn_mfma_f32_16x16x32_bf16(ah2, bb2[nt], t4acc[nt], 0, 0, 0);
    }
    // store prefetched chunk into the other buffer (disjoint from cur)
    if (c < 15) {
#pragma unroll
      for (int q = 0; q < 4; q++) {
        int flat = q * 2048 + tid * 8;
        *(bf16x8*)&Bs[nxt][flat >> 8][flat & 255] = pw3[q];
      }
      *(bf16x8*)&Ws4[nxt][w4row][w4seg] = pw4;
    }
    __syncthreads();
  }
  // epilogue: bf16 t4 = acc*dis, staged through Bs (dead) for full-line writes
  short* epi = (short*)&Bs[0][0][0];   // 64*64 shorts = 8 KB
#pragma unroll
  for (int r = 0; r < 4; r++) {
    int lr = w * 16 + rquad + r;
    int gr = row0 + lr;
    float sc = (gr < M) ? dis[gr] : 0.f;
#pragma unroll
    for (int nt = 0; nt < 4; nt++)
      epi[lr * 64 + nt * 16 + lm] = (short)f2bf(t4acc[nt][r] * sc);
  }
  __syncthreads();
  {
    int base = tid * 16;               // 4096 shorts / 256 threads
    int row = base >> 6, col = base & 63;
    int gr = row0 + row;
    if (gr < M) {
      *(bf16x8*)(T4 + (size_t)gr * 64 + col)     = *(bf16x8*)&epi[base];
      *(bf16x8*)(T4 + (size_t)gr * 64 + col + 8) = *(bf16x8*)&epi[base + 8];
    }
  }
}

// ---------------- Aggregation (dis-free; rows pre-scaled by dis) ----------------

template<int BR, int OSCL>
__global__ __launch_bounds__(256) void aggb64_k(const short* __restrict__ T, const float* __restrict__ dis,
                                                const int* __restrict__ off, const int* __restrict__ csr,
                                                const float* __restrict__ bias, short* __restrict__ Out, int n) {
  int wid = (blockIdx.x * 256 + threadIdx.x) >> 6;
  int lane = threadIdx.x & 63;
  if (wid >= n) return;
  float di = dis[wid];
  int e0 = off[wid], e1 = off[wid + 1];
  float acc = bf2f((unsigned short)T[(size_t)wid * 64 + lane]);
  int e = e0;
  for (; e + 8 <= e1; e += 8) {
    int j0 = csr[e], j1 = csr[e + 1], j2 = csr[e + 2], j3 = csr[e + 3];
    int j4 = csr[e + 4], j5 = csr[e + 5], j6 = csr[e + 6], j7 = csr[e + 7];
    float v0 = bf2f((unsigned short)T[(size_t)j0 * 64 + lane]);
    float v1 = bf2f((unsigned short)T[(size_t)j1 * 64 + lane]);
    float v2 = bf2f((unsigned short)T[(size_t)j2 * 64 + lane]);
    float v3 = bf2f((unsigned short)T[(size_t)j3 * 64 + lane]);
    float v4 = bf2f((unsigned short)T[(size_t)j4 * 64 + lane]);
    float v5 = bf2f((unsigned short)T[(size_t)j5 * 64 + lane]);
    float v6 = bf2f((unsigned short)T[(size_t)j6 * 64 + lane]);
    float v7 = bf2f((unsigned short)T[(size_t)j7 * 64 + lane]);
    acc += ((v0 + v1) + (v2 + v3)) + ((v4 + v5) + (v6 + v7));
  }
  for (; e + 4 <= e1; e += 4) {
    int j0 = csr[e], j1 = csr[e + 1], j2 = csr[e + 2], j3 = csr[e + 3];
    float v0 = bf2f((unsigned short)T[(size_t)j0 * 64 + lane]);
    float v1 = bf2f((unsigned short)T[(size_t)j1 * 64 + lane]);
    float v2 = bf2f((unsigned short)T[(size_t)j2 * 64 + lane]);
    float v3 = bf2f((unsigned short)T[(size_t)j3 * 64 + lane]);
    acc += (v0 + v1) + (v2 + v3);
  }
  for (; e < e1; e++) acc += bf2f((unsigned short)T[(size_t)csr[e] * 64 + lane]);
  float v = di * acc;
  if (BR) {
    v += bias[lane];
    v = (v >= 0.f) ? v : 0.01f * v;
  }
  if (OSCL) v *= di;
  Out[(size_t)wid * 64 + lane] = (short)f2bf(v);
}

// layer-4 tail fused: hn = LN( leaky(di*sum(t4b) + b4) + resid )   (t4b bf16)
__global__ __launch_bounds__(256) void agg64_ln_k(const short* __restrict__ T, const float* __restrict__ dis,
                                                  const int* __restrict__ off, const int* __restrict__ csr,
                                                  const float* __restrict__ bias, const float* __restrict__ resid,
                                                  const float* __restrict__ g, const float* __restrict__ b,
                                                  float* __restrict__ outh, int n) {
  int wid = (blockIdx.x * 256 + threadIdx.x) >> 6;
  int lane = threadIdx.x & 63;
  if (wid >= n) return;
  float di = dis[wid];
  int e0 = off[wid], e1 = off[wid + 1];
  float acc = bf2f((unsigned short)T[(size_t)wid * 64 + lane]);
  int e = e0;
  for (; e + 8 <= e1; e += 8) {
    int j0 = csr[e], j1 = csr[e + 1], j2 = csr[e + 2], j3 = csr[e + 3];
    int j4 = csr[e + 4], j5 = csr[e + 5], j6 = csr[e + 6], j7 = csr[e + 7];
    float v0 = bf2f((unsigned short)T[(size_t)j0 * 64 + lane]);
    float v1 = bf2f((unsigned short)T[(size_t)j1 * 64 + lane]);
    float v2 = bf2f((unsigned short)T[(size_t)j2 * 64 + lane]);
    float v3 = bf2f((unsigned short)T[(size_t)j3 * 64 + lane]);
    float v4 = bf2f((unsigned short)T[(size_t)j4 * 64 + lane]);
    float v5 = bf2f((unsigned short)T[(size_t)j5 * 64 + lane]);
    float v6 = bf2f((unsigned short)T[(size_t)j6 * 64 + lane]);
    float v7 = bf2f((unsigned short)T[(size_t)j7 * 64 + lane]);
    acc += ((v0 + v1) + (v2 + v3)) + ((v4 + v5) + (v6 + v7));
  }
  for (; e + 4 <= e1; e += 4) {
    int j0 = csr[e], j1 = csr[e + 1], j2 = csr[e + 2], j3 = csr[e + 3];
    float v0 = bf2f((unsigned short)T[(size_t)j0 * 64 + lane]);
    float v1 = bf2f((unsigned short)T[(size_t)j1 * 64 + lane]);
    float v2 = bf2f((unsigned short)T[(size_t)j2 * 64 + lane]);
    float v3 = bf2f((unsigned short)T[(size_t)j3 * 64 + lane]);
    acc += (v0 + v1) + (v2 + v3);
  }
  for (; e < e1; e++) acc += bf2f((unsigned short)T[(size_t)csr[e] * 64 + lane]);
  float v = di * acc + bias[lane];
  v = (v >= 0.f) ? v : 0.01f * v;
  v += resid[(size_t)wid * 64 + lane];
  float s = v, ss = v * v;
#pragma unroll
  for (int o = 32; o > 0; o >>= 1) {
    s += __shfl_xor(s, o);
    ss += __shfl_xor(ss, o);
  }
  float m = s * (1.f / 64.f);
  float var = ss * (1.f / 64.f) - m * m;
  float y = (v - m) * rsqrtf(var + 1e-5f) * g[lane] + b[lane];
  outh[(size_t)wid * 64 + lane] = y;
}

// bf16 gather for the 256-dim layer: z3 = di*(sum + self)
__global__ __launch_bounds__(256) void agg256b_k(const short* __restrict__ T, const float* __restrict__ dis,
                                                 const int* __restrict__ off, const int* __restrict__ csr,
                                                 short* __restrict__ Out, int n) {
  int wid = (blockIdx.x * 256 + threadIdx.x) >> 6;
  int lane = threadIdx.x & 63;
  if (wid >= n) return;
  float di = dis[wid];
  int e0 = off[wid], e1 = off[wid + 1];
  bf16x4 sf = *(const bf16x4*)&T[(size_t)wid * 256 + lane * 4];
  float a0 = bf2f((unsigned short)sf[0]);
  float a1 = bf2f((unsigned short)sf[1]);
  float a2 = bf2f((unsigned short)sf[2]);
  float a3 = bf2f((unsigned short)sf[3]);
  int e = e0;
  for (; e + 8 <= e1; e += 8) {
    bf16x4 t[8];
#pragma unroll
    for (int q = 0; q < 8; q++) t[q] = *(const bf16x4*)&T[(size_t)csr[e + q] * 256 + lane * 4];
#pragma unroll
    for (int q = 0; q < 8; q++) {
      a0 += bf2f((unsigned short)t[q][0]);
      a1 += bf2f((unsigned short)t[q][1]);
      a2 += bf2f((unsigned short)t[q][2]);
      a3 += bf2f((unsigned short)t[q][3]);
    }
  }
  for (; e + 4 <= e1; e += 4) {
    bf16x4 t[4];
#pragma unroll
    for (int q = 0; q < 4; q++) t[q] = *(const bf16x4*)&T[(size_t)csr[e + q] * 256 + lane * 4];
#pragma unroll
    for (int q = 0; q < 4; q++) {
      a0 += bf2f((unsigned short)t[q][0]);
      a1 += bf2f((unsigned short)t[q][1]);
      a2 += bf2f((unsigned short)t[q][2]);
      a3 += bf2f((unsigned short)t[q][3]);
    }
  }
  for (; e < e1; e++) {
    bf16x4 t = *(const bf16x4*)&T[(size_t)csr[e] * 256 + lane * 4];
    a0 += bf2f((unsigned short)t[0]);
    a1 += bf2f((unsigned short)t[1]);
    a2 += bf2f((unsigned short)t[2]);
    a3 += bf2f((unsigned short)t[3]);
  }
  bf16x4 o;
  o[0] = (short)f2bf(di * a0);
  o[1] = (short)f2bf(di * a1);
  o[2] = (short)f2bf(di * a2);
  o[3] = (short)f2bf(di * a3);
  *(bf16x4*)&Out[(size_t)wid * 256 + lane * 4] = o;
}

// ---------------- per-graph max pool + final MLP (fused, one block per graph) ----------------

__global__ __launch_bounds__(256) void pool_mlp_k(const float* __restrict__ hn,
                                                  const float* __restrict__ fc1W, const float* __restrict__ fc1b,
                                                  const float* __restrict__ fng, const float* __restrict__ fnb,
                                                  const float* __restrict__ fc2W, const float* __restrict__ fc2b,
                                                  float* __restrict__ out, int n) {
  const int G = 64;
  int g = blockIdx.x;
  int f = threadIdx.x & 63, c = threadIdx.x >> 6;
  long long s0 = ((long long)g * n + G - 1) / G;
  long long e0 = ((long long)(g + 1) * n + G - 1) / G;
  float m = -INFINITY;
  for (long long i = s0 + c; i < e0; i += 4) m = fmaxf(m, hn[(size_t)i * 64 + f]);
  __shared__ float red[4][64];
  __shared__ float ps[64], qs[64];
  red[c][f] = m;
  __syncthreads();
  if (c == 0) ps[f] = fmaxf(fmaxf(red[0][f], red[1][f]), fmaxf(red[2][f], red[3][f]));
  __syncthreads();
  if (threadIdx.x < 64) {
    int lane = threadIdx.x;
    float q = fc1b[lane];
#pragma unroll 8
    for (int k = 0; k < 64; k++) q = fmaf(ps[k], fc1W[k * 64 + lane], q);
    float s = q, ss = q * q;
#pragma unroll
    for (int o = 32; o > 0; o >>= 1) {
      s += __shfl_xor(s, o);
      ss += __shfl_xor(ss, o);
    }
    float mm = s * (1.f / 64.f);
    float var = ss * (1.f / 64.f) - mm * mm;
    float y = (q - mm) * rsqrtf(var + 1e-5f) * fng[lane] + fnb[lane];
    y = (y >= 0.f) ? y : 0.01f * y;
    qs[lane] = y;
    __builtin_amdgcn_wave_barrier();
    if (lane < 16) {
      float o = fc2b[lane];
#pragma unroll 8
      for (int k = 0; k < 64; k++) o = fmaf(qs[k], fc2W[k * 16 + lane], o);
      out[g * 16 + lane] = o;
    }
  }
}

// ---------------- launch ----------------

extern "C" void kernel_launch(void* const* d_in, const int* in_sizes, int n_in,
                              void* d_out, int out_size, void* d_ws, size_t ws_size,
                              hipStream_t stream) {
  const float* x   = (const float*)d_in[0];
  const int*   ei  = (const int*)d_in[1];
  const float* W1  = (const float*)d_in[3];
  const float* b1  = (const float*)d_in[4];
  const float* W2  = (const float*)d_in[5];
  const float* b2  = (const float*)d_in[6];
  const float* W3  = (const float*)d_in[7];
  const float* b3  = (const float*)d_in[8];
  const float* W4  = (const float*)d_in[9];
  const float* b4  = (const float*)d_in[10];
  const float* Wr  = (const float*)d_in[11];
  const float* br  = (const float*)d_in[12];
  const float* lng = (const float*)d_in[13];
  const float* lnb = (const float*)d_in[14];
  const float* f1W = (const float*)d_in[15];
  const float* f1b = (const float*)d_in[16];
  const float* fng = (const float*)d_in[17];
  const float* fnb = (const float*)d_in[18];
  const float* f2W = (const float*)d_in[19];
  const float* f2b = (const float*)d_in[20];

  int n = in_sizes[0] / 128;   // 50000
  int e = in_sizes[1] / 2;     // 400000
  const int* src = ei;
  const int* dst = ei + e;

  float* arena = (float*)d_ws;
  float* resid = arena;
  short* h2b   = (short*)(arena + (size_t)64 * n);
  short* t4b   = (short*)(arena + (size_t)64 * n);   // n x 64 bf16; h2b dead when written
  short* z3b   = (short*)(arena + (size_t)192 * n);
  float* hn    = arena + (size_t)192 * n;
  short* t1b   = (short*)(arena + (size_t)320 * n);
  short* h1b   = (short*)(arena + (size_t)352 * n);
  short* z2b   = (short*)(arena + (size_t)384 * n);
  float* dis   = arena + (size_t)448 * n;  // n
  int* cnt    = (int*)(dis + n);           // n
  int* off    = cnt + n;                   // n+1
  int* cursor = off + n + 1;               // n
  int* csr    = cursor + n;                // e
  int* bsum   = csr + e;                   // 256
  int* bpre   = bsum + 256;                // 256
  float* pool = (float*)(bpre + 256);      // 64*64 (layout keep)
  size_t wq = (((size_t)(pool + 4096)) + 15) & ~(size_t)15;
  short* wc1 = (short*)wq;                 // 64 x 128   (wc1||wcR = fused 128 x 128)
  short* wcR = wc1 + 8192;                 // 64 x 128
  short* wc2 = wcR + 8192;                 // 256 x 64
  short* wc3 = wc2 + 16384;                // 512 x 256
  short* wc4 = wc3 + 131072;               // 64 x 512
  size_t need = ((char*)(wc4 + 32768) - (char*)d_ws) + 64;
  if (ws_size < need) return;

  int nb_n = (n + 255) / 256;     // 196
  int nb_e = (e + 255) / 256;
  int nb_w = (n + 3) / 4;         // one wave per node
  int g_wide = (n + 63) / 64;     // 782
  int g_fused = (n + 127) / 128;  // 391

  // weights -> bf16 [N][K]
  wconv_k<<<960, 256, 0, stream>>>(W1, Wr, W2, W3, W4, wc1, wcR, wc2, wc3, wc4);

  // degree + CSR (hierarchical scan; dis fused into scan_c)
  hipMemsetAsync(cnt, 0, (size_t)n * sizeof(int), stream);
  count_k<<<nb_e, 256, 0, stream>>>(dst, cnt, e);
  scan_a<<<nb_n, 256, 0, stream>>>(cnt, bsum, n);
  scan_b<<<1, 256, 0, stream>>>(bsum, bpre, off + n, nb_n);
  scan_c<<<nb_n, 256, 0, stream>>>(cnt, bpre, off, cursor, dis, n);
  scatter_k<<<nb_e, 256, 0, stream>>>(src, dst, cursor, csr, e);

  // fused L1 + residual: t1b = bf16(dis*(x@W1)); resid = x@Wr + br
  mgemm<128, 128, 2, 2, 1, 0, 0, 0, 1, 1, 4><<<dim3(g_fused, 1), 256, 0, stream>>>(x, wc1, br, t1b, resid, dis, n);
  // h1b = bf16( dis * leaky(di*sum(t1) + b1) )
  aggb64_k<1, 1><<<nb_w, 256, 0, stream>>>(t1b, dis, off, csr, b1, h1b, n);
  // z2b = bf16( di * sum(h1) )
  aggb64_k<0, 0><<<nb_w, 256, 0, stream>>>(h1b, dis, off, csr, nullptr, z2b, n);
  // h2b = bf16( dis * leaky(z2@W2 + b2) )
  mgemm<64, 256, 1, 4, 1, 1, 1, 1, 0, 1, 5><<<dim3(g_wide, 1), 256, 0, stream>>>(z2b, wc2, b2, h2b, nullptr, dis, n);
  // z3b = bf16( di * sum(h2b) )
  agg256b_k<<<nb_w, 256, 0, stream>>>(h2b, dis, off, csr, z3b, n);
  // t4b = bf16( dis * (leaky(z3@W3+b3) @ W4) )   (h3 on-chip, ping-pong pipeline)
  fused34_k<<<g_wide, 256, 0, stream>>>(z3b, wc3, b3, wc4, dis, t4b, n);
  // hn = LN( leaky(di*sum(t4b) + b4) + resid )
  agg64_ln_k<<<nb_w, 256, 0, stream>>>(t4b, dis, off, csr, b4, resid, lng, lnb, hn, n);
  // pool + MLP fused
  pool_mlp_k<<<64, 256, 0, stream>>>(hn, f1W, f1b, fng, fnb, f2W, f2b, (float*)d_out, n);
}